// Round 2
// baseline (683.716 us; speedup 1.0000x reference)
//
#include <hip/hip_runtime.h>
#include <hip/hip_bf16.h>
#include <stdint.h>

#define NN 100000
#define NE 1600000
#define NB 98                   // ceil(NN/1024) scan blocks

// ---------------- edge_index width detection (int32 vs int64) ----------------
// If the harness passes int64 (reference dtype), every high 32-bit word is 0
// (values in [0,1e5)). For genuine int32 data, 16 consecutive odd words all
// being zero has probability ~(1e-5)^16 ~ 0. flag=1 => int64 layout.

__global__ void k_detect(const int* __restrict__ ei, int* __restrict__ flag) {
    if (threadIdx.x == 0) {
        int z = 0;
#pragma unroll
        for (int i = 0; i < 16; ++i) z |= ei[2 * i + 1];
        flag[0] = (z == 0) ? 1 : 0;
    }
}

__device__ __forceinline__ int edge_src(const int* ei, int is64, int e) {
    return is64 ? ei[2 * e] : ei[e];
}
__device__ __forceinline__ int edge_dst(const int* ei, int is64, int e) {
    return is64 ? ei[2 * NE + 2 * e] : ei[NE + e];
}

// ---------------- CSR build ----------------

__global__ void k_count(const int* __restrict__ ei, const int* __restrict__ flag,
                        int* __restrict__ cnt) {
    int e = blockIdx.x * 256 + threadIdx.x;
    int is64 = flag[0];
    if (e < NE) atomicAdd(&cnt[edge_dst(ei, is64, e)], 1);
}

__global__ void k_dinv(const int* __restrict__ cnt, float* __restrict__ dinv) {
    int n = blockIdx.x * 256 + threadIdx.x;
    if (n < NN) dinv[n] = rsqrtf((float)cnt[n] + 1.0f);
}

__global__ void k_scan1(const int* __restrict__ cnt, int* __restrict__ bsum) {
    __shared__ int sh[256];
    int t = threadIdx.x;
    int base = blockIdx.x * 1024 + t * 4;
    int s = 0;
#pragma unroll
    for (int j = 0; j < 4; ++j) { int i = base + j; if (i < NN) s += cnt[i]; }
    sh[t] = s; __syncthreads();
    for (int off = 128; off > 0; off >>= 1) {
        if (t < off) sh[t] += sh[t + off];
        __syncthreads();
    }
    if (t == 0) bsum[blockIdx.x] = sh[0];
}

__global__ void k_scan2(const int* __restrict__ bsum, int* __restrict__ boff,
                        int* __restrict__ rs) {
    if (threadIdx.x == 0) {
        int run = 0;
        for (int b = 0; b < NB; ++b) { boff[b] = run; run += bsum[b]; }
        rs[NN] = run;   // == NE
    }
}

__global__ void k_scan3(const int* __restrict__ cnt, const int* __restrict__ boff,
                        int* __restrict__ rs, int* __restrict__ cur) {
    __shared__ int sh[256];
    int t = threadIdx.x;
    int base = blockIdx.x * 1024 + t * 4;
    int v[4]; int s = 0;
#pragma unroll
    for (int j = 0; j < 4; ++j) { int i = base + j; v[j] = (i < NN) ? cnt[i] : 0; s += v[j]; }
    sh[t] = s; __syncthreads();
    for (int off = 1; off < 256; off <<= 1) {
        int tmp = (t >= off) ? sh[t - off] : 0;
        __syncthreads();
        sh[t] += tmp;
        __syncthreads();
    }
    int run = sh[t] - s + boff[blockIdx.x];   // exclusive prefix for this thread
#pragma unroll
    for (int j = 0; j < 4; ++j) {
        int i = base + j;
        if (i < NN) { rs[i] = run; cur[i] = run; run += v[j]; }
    }
}

__global__ void k_fill(const int* __restrict__ ei, const int* __restrict__ flag,
                       const float* __restrict__ dinv, int* __restrict__ cur,
                       uint2* __restrict__ csr) {
    int e = blockIdx.x * 256 + threadIdx.x;
    int is64 = flag[0];
    if (e < NE) {
        int s = edge_src(ei, is64, e);
        int d = edge_dst(ei, is64, e);
        int pos = atomicAdd(&cur[d], 1);
        uint2 p;
        p.x = __float_as_uint(dinv[s]);     // src-side norm factor
        p.y = (unsigned)s * 256u;           // byte offset of fp32 h row (64*4B)
        csr[pos] = p;
    }
}

// ---------------- fp32 GEMM: H[N,64] = X[N,64] @ W[64,64] (VALU, W in LDS) ----------------

__global__ void __launch_bounds__(256) k_gemm(const float* __restrict__ X,
                                              const float* __restrict__ W,
                                              float* __restrict__ H) {
    __shared__ float Ws[64 * 64];
    for (int i = threadIdx.x; i < 4096; i += 256) Ws[i] = W[i];
    __syncthreads();
    int lane = threadIdx.x & 63;
    int wid = (blockIdx.x * blockDim.x + threadIdx.x) >> 6;
    int nw = (gridDim.x * blockDim.x) >> 6;
    const int ngroups = NN / 4;   // 25000, NN % 4 == 0
    for (int g = wid; g < ngroups; g += nw) {
        int n0 = g * 4;
        float a0 = 0.f, a1 = 0.f, a2 = 0.f, a3 = 0.f;
#pragma unroll 4
        for (int k4 = 0; k4 < 16; ++k4) {
            float4 x0 = *(const float4*)&X[(n0 + 0) * 64 + k4 * 4];
            float4 x1 = *(const float4*)&X[(n0 + 1) * 64 + k4 * 4];
            float4 x2 = *(const float4*)&X[(n0 + 2) * 64 + k4 * 4];
            float4 x3 = *(const float4*)&X[(n0 + 3) * 64 + k4 * 4];
            const float* wp = &Ws[k4 * 4 * 64 + lane];
            float w0 = wp[0], w1 = wp[64], w2 = wp[128], w3 = wp[192];
            a0 += x0.x * w0; a0 += x0.y * w1; a0 += x0.z * w2; a0 += x0.w * w3;
            a1 += x1.x * w0; a1 += x1.y * w1; a1 += x1.z * w2; a1 += x1.w * w3;
            a2 += x2.x * w0; a2 += x2.y * w1; a2 += x2.z * w2; a2 += x2.w * w3;
            a3 += x3.x * w0; a3 += x3.y * w1; a3 += x3.z * w2; a3 += x3.w * w3;
        }
        H[(n0 + 0) * 64 + lane] = a0;
        H[(n0 + 1) * 64 + lane] = a1;
        H[(n0 + 2) * 64 + lane] = a2;
        H[(n0 + 3) * 64 + lane] = a3;
    }
}

// ---------------- aggregation: one wave per node, lane = feature (fp32) ----------------

__global__ void __launch_bounds__(256) k_agg(const float* __restrict__ h,
                                             const int* __restrict__ rs,
                                             const uint2* __restrict__ csr,
                                             const float* __restrict__ dinv,
                                             const float* __restrict__ bias,
                                             float* __restrict__ out) {
    int wid = (blockIdx.x * blockDim.x + threadIdx.x) >> 6;
    int lane = threadIdx.x & 63;
    if (wid >= NN) return;
    int node = wid;
    float dn = dinv[node];
    int e0 = rs[node], e1 = rs[node + 1];
    float acc = h[node * 64 + lane] * dn;   // self loop (×dn again below => dn^2)
    const char* hb = (const char*)h;
    for (int e = e0; e < e1; ++e) {
        uint2 p = csr[e];                                    // wave-uniform 8B load
        acc += *(const float*)(hb + p.y + lane * 4) * __uint_as_float(p.x);
    }
    acc = acc * dn + bias[lane];
    out[node * 64 + lane] = fmaxf(acc, 0.0f);                // ReLU (both layers)
}

// ---------------- launch ----------------

extern "C" void kernel_launch(void* const* d_in, const int* in_sizes, int n_in,
                              void* d_out, int out_size, void* d_ws, size_t ws_size,
                              hipStream_t stream) {
    const float* x  = (const float*)d_in[0];            // [NN,64] fp32
    const int* ei   = (const int*)d_in[1];              // [2,NE] int32 (or int64 — detected)
    const float* W1 = (const float*)d_in[2];            // [64,64] fp32
    const float* b1 = (const float*)d_in[3];            // [64]
    const float* W2 = (const float*)d_in[4];
    const float* b2 = (const float*)d_in[5];

    char* ws = (char*)d_ws;
    size_t off = 0;
    auto alloc = [&](size_t bytes) -> char* {
        char* p = ws + off;
        off = (off + bytes + 511) & ~(size_t)511;
        return p;
    };
    int*   cnt  = (int*)alloc((size_t)NN * 4);
    float* dinv = (float*)alloc((size_t)NN * 4);
    int*   rs   = (int*)alloc((size_t)(NN + 1) * 4);
    int*   cur  = (int*)alloc((size_t)NN * 4);
    int*   bsum = (int*)alloc((size_t)NB * 4);
    int*   boff = (int*)alloc((size_t)NB * 4);
    int*   flag = (int*)alloc(64);
    uint2* csr  = (uint2*)alloc((size_t)NE * 8);        // 12.8 MB
    float* hA   = (float*)alloc((size_t)NN * 64 * 4);   // 25.6 MB
    float* hB   = (float*)d_out;                        // reuse d_out as layer-1 activation

    hipMemsetAsync(cnt, 0, (size_t)NN * 4, stream);
    k_detect<<<1, 64, 0, stream>>>(ei, flag);
    k_count<<<(NE + 255) / 256, 256, 0, stream>>>(ei, flag, cnt);
    k_dinv<<<(NN + 255) / 256, 256, 0, stream>>>(cnt, dinv);
    k_scan1<<<NB, 256, 0, stream>>>(cnt, bsum);
    k_scan2<<<1, 64, 0, stream>>>(bsum, boff, rs);
    k_scan3<<<NB, 256, 0, stream>>>(cnt, boff, rs, cur);
    k_fill<<<(NE + 255) / 256, 256, 0, stream>>>(ei, flag, dinv, cur, csr);

    // layer 1: hA = x @ W1 ; hB(=d_out) = relu(agg(hA) + b1)
    k_gemm<<<256, 256, 0, stream>>>(x, W1, hA);
    k_agg<<<(NN * 64) / 256, 256, 0, stream>>>(hA, rs, csr, dinv, b1, hB);
    // layer 2: hA = hB @ W2 ; out = relu(agg(hA) + b2)
    k_gemm<<<256, 256, 0, stream>>>(hB, W2, hA);
    k_agg<<<(NN * 64) / 256, 256, 0, stream>>>(hA, rs, csr, dinv, b2, (float*)d_out);
}

// Round 3
// 494.613 us; speedup vs baseline: 1.3823x; 1.3823x over previous
//
#include <hip/hip_runtime.h>
#include <hip/hip_bf16.h>
#include <stdint.h>

#define NN 100000
#define NE 1600000
#define NB 98                   // ceil(NN/1024) scan blocks

// ---------------- edge_index width detection (int32 vs int64) ----------------

__global__ void k_detect(const int* __restrict__ ei, int* __restrict__ flag) {
    if (threadIdx.x == 0) {
        int z = 0;
#pragma unroll
        for (int i = 0; i < 16; ++i) z |= ei[2 * i + 1];
        flag[0] = (z == 0) ? 1 : 0;
    }
}

// ---------------- CSR build ----------------

__global__ void k_count(const int* __restrict__ ei, const int* __restrict__ flag,
                        int* __restrict__ cnt) {
    int e = blockIdx.x * 256 + threadIdx.x;
    if (e >= NE) return;
    int is64 = flag[0];
    int d = is64 ? ((const int2*)ei)[NE + e].x : ei[NE + e];
    atomicAdd(&cnt[d], 1);
}

__global__ void k_dinv(const int* __restrict__ cnt, float* __restrict__ dinv) {
    int n = blockIdx.x * 256 + threadIdx.x;
    if (n < NN) dinv[n] = rsqrtf((float)cnt[n] + 1.0f);
}

__global__ void k_scan1(const int* __restrict__ cnt, int* __restrict__ bsum) {
    __shared__ int sh[256];
    int t = threadIdx.x;
    int base = blockIdx.x * 1024 + t * 4;
    int s = 0;
#pragma unroll
    for (int j = 0; j < 4; ++j) { int i = base + j; if (i < NN) s += cnt[i]; }
    sh[t] = s; __syncthreads();
    for (int off = 128; off > 0; off >>= 1) {
        if (t < off) sh[t] += sh[t + off];
        __syncthreads();
    }
    if (t == 0) bsum[blockIdx.x] = sh[0];
}

// one-wave exclusive scan over NB<=128 block sums (replaces serial loop)
__global__ void k_scan2(const int* __restrict__ bsum, int* __restrict__ boff,
                        int* __restrict__ rs) {
    int l = threadIdx.x;                 // 64 threads
    int a = (l < NB) ? bsum[l] : 0;
    int b = (64 + l < NB) ? bsum[64 + l] : 0;
    int ia = a, ib = b;
    for (int off = 1; off < 64; off <<= 1) {
        int t = __shfl_up(ia, off);
        if (l >= off) ia += t;
        t = __shfl_up(ib, off);
        if (l >= off) ib += t;
    }
    int tot_a = __shfl(ia, 63);
    if (l < NB) boff[l] = ia - a;                    // exclusive
    if (64 + l < NB) boff[64 + l] = tot_a + ib - b;
    if (l == 0) rs[NN] = NE;
}

__global__ void k_scan3(const int* __restrict__ cnt, const int* __restrict__ boff,
                        int* __restrict__ rs, int* __restrict__ cur) {
    __shared__ int sh[256];
    int t = threadIdx.x;
    int base = blockIdx.x * 1024 + t * 4;
    int v[4]; int s = 0;
#pragma unroll
    for (int j = 0; j < 4; ++j) { int i = base + j; v[j] = (i < NN) ? cnt[i] : 0; s += v[j]; }
    sh[t] = s; __syncthreads();
    for (int off = 1; off < 256; off <<= 1) {
        int tmp = (t >= off) ? sh[t - off] : 0;
        __syncthreads();
        sh[t] += tmp;
        __syncthreads();
    }
    int run = sh[t] - s + boff[blockIdx.x];
#pragma unroll
    for (int j = 0; j < 4; ++j) {
        int i = base + j;
        if (i < NN) { rs[i] = run; cur[i] = run; run += v[j]; }
    }
}

// csr entry: src index in bits 0..19, src in-degree (capped 4095) in bits 20..31.
// k_agg recomputes dinv_src = rsqrtf(deg+1) — bit-identical to k_dinv's value.
__global__ void k_fill(const int* __restrict__ ei, const int* __restrict__ flag,
                       const int* __restrict__ cnt, int* __restrict__ cur,
                       unsigned* __restrict__ csr) {
    int e = blockIdx.x * 256 + threadIdx.x;
    if (e >= NE) return;
    int is64 = flag[0];
    int s, d;
    if (is64) {
        s = ((const int2*)ei)[e].x;
        d = ((const int2*)ei)[NE + e].x;
    } else {
        s = ei[e];
        d = ei[NE + e];
    }
    int pos = atomicAdd(&cur[d], 1);
    unsigned deg = (unsigned)min(cnt[s], 4095);
    csr[pos] = (unsigned)s | (deg << 20);
}

// ---------------- fp32 GEMM: H[N,64] = X[N,64] @ W[64,64] (VALU, W in LDS) ----------------

__global__ void __launch_bounds__(256) k_gemm(const float* __restrict__ X,
                                              const float* __restrict__ W,
                                              float* __restrict__ H) {
    __shared__ float Ws[64 * 64];
    for (int i = threadIdx.x; i < 4096; i += 256) Ws[i] = W[i];
    __syncthreads();
    int lane = threadIdx.x & 63;
    int wid = (blockIdx.x * blockDim.x + threadIdx.x) >> 6;
    int nw = (gridDim.x * blockDim.x) >> 6;
    const int ngroups = NN / 4;
    for (int g = wid; g < ngroups; g += nw) {
        int n0 = g * 4;
        float a0 = 0.f, a1 = 0.f, a2 = 0.f, a3 = 0.f;
#pragma unroll 4
        for (int k4 = 0; k4 < 16; ++k4) {
            float4 x0 = *(const float4*)&X[(n0 + 0) * 64 + k4 * 4];
            float4 x1 = *(const float4*)&X[(n0 + 1) * 64 + k4 * 4];
            float4 x2 = *(const float4*)&X[(n0 + 2) * 64 + k4 * 4];
            float4 x3 = *(const float4*)&X[(n0 + 3) * 64 + k4 * 4];
            const float* wp = &Ws[k4 * 4 * 64 + lane];
            float w0 = wp[0], w1 = wp[64], w2 = wp[128], w3 = wp[192];
            a0 += x0.x * w0; a0 += x0.y * w1; a0 += x0.z * w2; a0 += x0.w * w3;
            a1 += x1.x * w0; a1 += x1.y * w1; a1 += x1.z * w2; a1 += x1.w * w3;
            a2 += x2.x * w0; a2 += x2.y * w1; a2 += x2.z * w2; a2 += x2.w * w3;
            a3 += x3.x * w0; a3 += x3.y * w1; a3 += x3.z * w2; a3 += x3.w * w3;
        }
        H[(n0 + 0) * 64 + lane] = a0;
        H[(n0 + 1) * 64 + lane] = a1;
        H[(n0 + 2) * 64 + lane] = a2;
        H[(n0 + 3) * 64 + lane] = a3;
    }
}

// ---------------- aggregation: one wave per node, 16 lanes x float4 per row,
// ---------------- 4 lane-groups process 4 edges concurrently, unrolled x2 ----

__global__ void __launch_bounds__(256) k_agg(const float4* __restrict__ h4,
                                             const int* __restrict__ rs,
                                             const unsigned* __restrict__ csr,
                                             const float* __restrict__ dinv,
                                             const float* __restrict__ bias,
                                             float4* __restrict__ out4) {
    int wid = (blockIdx.x * blockDim.x + threadIdx.x) >> 6;
    int lane = threadIdx.x & 63;
    int node = __builtin_amdgcn_readfirstlane(wid);
    if (node >= NN) return;
    int g = lane >> 4;        // edge-slot group 0..3
    int fl = lane & 15;       // feature quad 0..15
    float dn = dinv[node];
    int e0 = rs[node], e1 = rs[node + 1];
    float4 hrow = h4[node * 16 + fl];          // self row (broadcast within group)
    float ax = 0.f, ay = 0.f, az = 0.f, aw = 0.f;
    int e = e0 + g;
    for (; e + 4 < e1; e += 8) {               // two edges per group in flight
        unsigned p0 = csr[e];
        unsigned p1 = csr[e + 4];
        float4 r0 = h4[(p0 & 0xFFFFFu) * 16 + fl];
        float4 r1 = h4[(p1 & 0xFFFFFu) * 16 + fl];
        float w0 = rsqrtf((float)(p0 >> 20) + 1.0f);
        float w1 = rsqrtf((float)(p1 >> 20) + 1.0f);
        ax += r0.x * w0; ay += r0.y * w0; az += r0.z * w0; aw += r0.w * w0;
        ax += r1.x * w1; ay += r1.y * w1; az += r1.z * w1; aw += r1.w * w1;
    }
    if (e < e1) {
        unsigned p0 = csr[e];
        float4 r0 = h4[(p0 & 0xFFFFFu) * 16 + fl];
        float w0 = rsqrtf((float)(p0 >> 20) + 1.0f);
        ax += r0.x * w0; ay += r0.y * w0; az += r0.z * w0; aw += r0.w * w0;
    }
    // butterfly: sum the 4 lane-groups (lanes l, l^16, l^32, l^48)
    ax += __shfl_xor(ax, 16); ay += __shfl_xor(ay, 16);
    az += __shfl_xor(az, 16); aw += __shfl_xor(aw, 16);
    ax += __shfl_xor(ax, 32); ay += __shfl_xor(ay, 32);
    az += __shfl_xor(az, 32); aw += __shfl_xor(aw, 32);
    if (lane < 16) {
        const float4 b4 = *(const float4*)&bias[fl * 4];
        float4 res;
        res.x = fmaxf((ax + hrow.x * dn) * dn + b4.x, 0.f);
        res.y = fmaxf((ay + hrow.y * dn) * dn + b4.y, 0.f);
        res.z = fmaxf((az + hrow.z * dn) * dn + b4.z, 0.f);
        res.w = fmaxf((aw + hrow.w * dn) * dn + b4.w, 0.f);
        out4[node * 16 + fl] = res;
    }
}

// ---------------- launch ----------------

extern "C" void kernel_launch(void* const* d_in, const int* in_sizes, int n_in,
                              void* d_out, int out_size, void* d_ws, size_t ws_size,
                              hipStream_t stream) {
    const float* x  = (const float*)d_in[0];            // [NN,64] fp32
    const int* ei   = (const int*)d_in[1];              // [2,NE] int32/int64 (detected)
    const float* W1 = (const float*)d_in[2];
    const float* b1 = (const float*)d_in[3];
    const float* W2 = (const float*)d_in[4];
    const float* b2 = (const float*)d_in[5];

    char* ws = (char*)d_ws;
    size_t off = 0;
    auto alloc = [&](size_t bytes) -> char* {
        char* p = ws + off;
        off = (off + bytes + 511) & ~(size_t)511;
        return p;
    };
    int*      cnt  = (int*)alloc((size_t)NN * 4);
    float*    dinv = (float*)alloc((size_t)NN * 4);
    int*      rs   = (int*)alloc((size_t)(NN + 1) * 4);
    int*      cur  = (int*)alloc((size_t)NN * 4);
    int*      bsum = (int*)alloc((size_t)NB * 4);
    int*      boff = (int*)alloc((size_t)NB * 4);
    int*      flag = (int*)alloc(64);
    unsigned* csr  = (unsigned*)alloc((size_t)NE * 4);  // 6.4 MB packed
    float*    hA   = (float*)alloc((size_t)NN * 64 * 4);
    float*    hB   = (float*)d_out;                     // reuse d_out as layer-1 act

    hipMemsetAsync(cnt, 0, (size_t)NN * 4, stream);
    k_detect<<<1, 64, 0, stream>>>(ei, flag);
    k_count<<<(NE + 255) / 256, 256, 0, stream>>>(ei, flag, cnt);
    k_dinv<<<(NN + 255) / 256, 256, 0, stream>>>(cnt, dinv);
    k_scan1<<<NB, 256, 0, stream>>>(cnt, bsum);
    k_scan2<<<1, 64, 0, stream>>>(bsum, boff, rs);
    k_scan3<<<NB, 256, 0, stream>>>(cnt, boff, rs, cur);
    k_fill<<<(NE + 255) / 256, 256, 0, stream>>>(ei, flag, cnt, cur, csr);

    // layer 1
    k_gemm<<<1568, 256, 0, stream>>>(x, W1, hA);
    k_agg<<<(NN * 64) / 256, 256, 0, stream>>>((const float4*)hA, rs, csr, dinv, b1,
                                               (float4*)hB);
    // layer 2
    k_gemm<<<1568, 256, 0, stream>>>(hB, W2, hA);
    k_agg<<<(NN * 64) / 256, 256, 0, stream>>>((const float4*)hA, rs, csr, dinv, b2,
                                               (float4*)d_out);
}

// Round 4
// 420.568 us; speedup vs baseline: 1.6257x; 1.1761x over previous
//
#include <hip/hip_runtime.h>
#include <hip/hip_bf16.h>
#include <stdint.h>

#define NN 100000
#define NE 1600000
#define NB 98                   // ceil(NN/1024) scan blocks

// ---------------- edge_index width detection (int32 vs int64) ----------------

__global__ void k_detect(const int* __restrict__ ei, int* __restrict__ flag) {
    if (threadIdx.x == 0) {
        int z = 0;
#pragma unroll
        for (int i = 0; i < 16; ++i) z |= ei[2 * i + 1];
        flag[0] = (z == 0) ? 1 : 0;
    }
}

// ---------------- CSR build ----------------
// k_count: histogram in-degree AND record each edge's rank within its dst
// segment (the atomic's return value). rank write is coalesced.

__global__ void k_count(const int* __restrict__ ei, const int* __restrict__ flag,
                        int* __restrict__ cnt, int* __restrict__ rank) {
    int e = blockIdx.x * 256 + threadIdx.x;
    if (e >= NE) return;
    int is64 = flag[0];
    int d = is64 ? ((const int2*)ei)[NE + e].x : ei[NE + e];
    rank[e] = atomicAdd(&cnt[d], 1);
}

// block-level partial sums for the scan + dinv computation (fused)
__global__ void k_scan1(const int* __restrict__ cnt, int* __restrict__ bsum,
                        float* __restrict__ dinv) {
    __shared__ int sh[256];
    int t = threadIdx.x;
    int base = blockIdx.x * 1024 + t * 4;
    int s = 0;
#pragma unroll
    for (int j = 0; j < 4; ++j) {
        int i = base + j;
        if (i < NN) {
            int c = cnt[i];
            s += c;
            dinv[i] = rsqrtf((float)c + 1.0f);
        }
    }
    sh[t] = s; __syncthreads();
    for (int off = 128; off > 0; off >>= 1) {
        if (t < off) sh[t] += sh[t + off];
        __syncthreads();
    }
    if (t == 0) bsum[blockIdx.x] = sh[0];
}

// one-wave exclusive scan over NB<=128 block sums
__global__ void k_scan2(const int* __restrict__ bsum, int* __restrict__ boff,
                        int* __restrict__ rs) {
    int l = threadIdx.x;                 // 64 threads
    int a = (l < NB) ? bsum[l] : 0;
    int b = (64 + l < NB) ? bsum[64 + l] : 0;
    int ia = a, ib = b;
    for (int off = 1; off < 64; off <<= 1) {
        int t = __shfl_up(ia, off);
        if (l >= off) ia += t;
        t = __shfl_up(ib, off);
        if (l >= off) ib += t;
    }
    int tot_a = __shfl(ia, 63);
    if (l < NB) boff[l] = ia - a;
    if (64 + l < NB) boff[64 + l] = tot_a + ib - b;
    if (l == 0) rs[NN] = NE;
}

__global__ void k_scan3(const int* __restrict__ cnt, const int* __restrict__ boff,
                        int* __restrict__ rs) {
    __shared__ int sh[256];
    int t = threadIdx.x;
    int base = blockIdx.x * 1024 + t * 4;
    int v[4]; int s = 0;
#pragma unroll
    for (int j = 0; j < 4; ++j) { int i = base + j; v[j] = (i < NN) ? cnt[i] : 0; s += v[j]; }
    sh[t] = s; __syncthreads();
    for (int off = 1; off < 256; off <<= 1) {
        int tmp = (t >= off) ? sh[t - off] : 0;
        __syncthreads();
        sh[t] += tmp;
        __syncthreads();
    }
    int run = sh[t] - s + boff[blockIdx.x];
#pragma unroll
    for (int j = 0; j < 4; ++j) {
        int i = base + j;
        if (i < NN) { rs[i] = run; run += v[j]; }
    }
}

// csr entry: (src*16) in bits 0..20 (direct float4-row base), src in-degree
// (capped 2047) in bits 21..31. Atomic-free: pos = rs[d] + rank[e].
__global__ void k_fill(const int* __restrict__ ei, const int* __restrict__ flag,
                       const int* __restrict__ cnt, const int* __restrict__ rs,
                       const int* __restrict__ rank, unsigned* __restrict__ csr) {
    int e = blockIdx.x * 256 + threadIdx.x;
    if (e >= NE) return;
    int is64 = flag[0];
    int s, d;
    if (is64) {
        s = ((const int2*)ei)[e].x;
        d = ((const int2*)ei)[NE + e].x;
    } else {
        s = ei[e];
        d = ei[NE + e];
    }
    int pos = rs[d] + rank[e];
    unsigned deg = (unsigned)min(cnt[s], 2047);
    csr[pos] = ((unsigned)s << 4) | (deg << 21);
}

// ---------------- fp32 GEMM: H[N,64] = X[N,64] @ W[64,64] (VALU, W in LDS) ----------------

__global__ void __launch_bounds__(256) k_gemm(const float* __restrict__ X,
                                              const float* __restrict__ W,
                                              float* __restrict__ H) {
    __shared__ float Ws[64 * 64];
    for (int i = threadIdx.x; i < 4096; i += 256) Ws[i] = W[i];
    __syncthreads();
    int lane = threadIdx.x & 63;
    int wid = (blockIdx.x * blockDim.x + threadIdx.x) >> 6;
    int nw = (gridDim.x * blockDim.x) >> 6;
    const int ngroups = NN / 4;
    for (int g = wid; g < ngroups; g += nw) {
        int n0 = g * 4;
        float a0 = 0.f, a1 = 0.f, a2 = 0.f, a3 = 0.f;
#pragma unroll 4
        for (int k4 = 0; k4 < 16; ++k4) {
            float4 x0 = *(const float4*)&X[(n0 + 0) * 64 + k4 * 4];
            float4 x1 = *(const float4*)&X[(n0 + 1) * 64 + k4 * 4];
            float4 x2 = *(const float4*)&X[(n0 + 2) * 64 + k4 * 4];
            float4 x3 = *(const float4*)&X[(n0 + 3) * 64 + k4 * 4];
            const float* wp = &Ws[k4 * 4 * 64 + lane];
            float w0 = wp[0], w1 = wp[64], w2 = wp[128], w3 = wp[192];
            a0 += x0.x * w0; a0 += x0.y * w1; a0 += x0.z * w2; a0 += x0.w * w3;
            a1 += x1.x * w0; a1 += x1.y * w1; a1 += x1.z * w2; a1 += x1.w * w3;
            a2 += x2.x * w0; a2 += x2.y * w1; a2 += x2.z * w2; a2 += x2.w * w3;
            a3 += x3.x * w0; a3 += x3.y * w1; a3 += x3.z * w2; a3 += x3.w * w3;
        }
        H[(n0 + 0) * 64 + lane] = a0;
        H[(n0 + 1) * 64 + lane] = a1;
        H[(n0 + 2) * 64 + lane] = a2;
        H[(n0 + 3) * 64 + lane] = a3;
    }
}

// ---------------- aggregation: one wave per node, 16 lanes x float4 per row,
// 4 lane-groups x 4-deep unroll => 16 row-gathers in flight per wave ----------

__global__ void __launch_bounds__(256) k_agg(const float4* __restrict__ h4,
                                             const int* __restrict__ rs,
                                             const unsigned* __restrict__ csr,
                                             const float* __restrict__ dinv,
                                             const float* __restrict__ bias,
                                             float4* __restrict__ out4) {
    int wid = (blockIdx.x * blockDim.x + threadIdx.x) >> 6;
    int lane = threadIdx.x & 63;
    int node = __builtin_amdgcn_readfirstlane(wid);
    if (node >= NN) return;
    int g = lane >> 4;        // edge-slot group 0..3
    int fl = lane & 15;       // feature quad 0..15
    float dn = dinv[node];
    int e0 = rs[node], e1 = rs[node + 1];
    float4 hrow = h4[node * 16 + fl];          // self row
    float ax = 0.f, ay = 0.f, az = 0.f, aw = 0.f;
    int e = e0 + g;
    for (; e + 12 < e1; e += 16) {             // 4 edges per group in flight
        unsigned p0 = csr[e];
        unsigned p1 = csr[e + 4];
        unsigned p2 = csr[e + 8];
        unsigned p3 = csr[e + 12];
        float4 r0 = h4[(p0 & 0x1FFFFFu) + fl];
        float4 r1 = h4[(p1 & 0x1FFFFFu) + fl];
        float4 r2 = h4[(p2 & 0x1FFFFFu) + fl];
        float4 r3 = h4[(p3 & 0x1FFFFFu) + fl];
        float w0 = rsqrtf((float)(p0 >> 21) + 1.0f);
        float w1 = rsqrtf((float)(p1 >> 21) + 1.0f);
        float w2 = rsqrtf((float)(p2 >> 21) + 1.0f);
        float w3 = rsqrtf((float)(p3 >> 21) + 1.0f);
        ax += r0.x * w0; ay += r0.y * w0; az += r0.z * w0; aw += r0.w * w0;
        ax += r1.x * w1; ay += r1.y * w1; az += r1.z * w1; aw += r1.w * w1;
        ax += r2.x * w2; ay += r2.y * w2; az += r2.z * w2; aw += r2.w * w2;
        ax += r3.x * w3; ay += r3.y * w3; az += r3.z * w3; aw += r3.w * w3;
    }
    for (; e < e1; e += 4) {
        unsigned p0 = csr[e];
        float4 r0 = h4[(p0 & 0x1FFFFFu) + fl];
        float w0 = rsqrtf((float)(p0 >> 21) + 1.0f);
        ax += r0.x * w0; ay += r0.y * w0; az += r0.z * w0; aw += r0.w * w0;
    }
    // butterfly: sum the 4 lane-groups (lanes l, l^16, l^32, l^48)
    ax += __shfl_xor(ax, 16); ay += __shfl_xor(ay, 16);
    az += __shfl_xor(az, 16); aw += __shfl_xor(aw, 16);
    ax += __shfl_xor(ax, 32); ay += __shfl_xor(ay, 32);
    az += __shfl_xor(az, 32); aw += __shfl_xor(aw, 32);
    if (lane < 16) {
        const float4 b4 = *(const float4*)&bias[fl * 4];
        float4 res;
        res.x = fmaxf((ax + hrow.x * dn) * dn + b4.x, 0.f);
        res.y = fmaxf((ay + hrow.y * dn) * dn + b4.y, 0.f);
        res.z = fmaxf((az + hrow.z * dn) * dn + b4.z, 0.f);
        res.w = fmaxf((aw + hrow.w * dn) * dn + b4.w, 0.f);
        out4[node * 16 + fl] = res;
    }
}

// ---------------- launch ----------------

extern "C" void kernel_launch(void* const* d_in, const int* in_sizes, int n_in,
                              void* d_out, int out_size, void* d_ws, size_t ws_size,
                              hipStream_t stream) {
    const float* x  = (const float*)d_in[0];            // [NN,64] fp32
    const int* ei   = (const int*)d_in[1];              // [2,NE] int32/int64 (detected)
    const float* W1 = (const float*)d_in[2];
    const float* b1 = (const float*)d_in[3];
    const float* W2 = (const float*)d_in[4];
    const float* b2 = (const float*)d_in[5];

    char* ws = (char*)d_ws;
    size_t off = 0;
    auto alloc = [&](size_t bytes) -> char* {
        char* p = ws + off;
        off = (off + bytes + 511) & ~(size_t)511;
        return p;
    };
    int*      cnt  = (int*)alloc((size_t)NN * 4);
    float*    dinv = (float*)alloc((size_t)NN * 4);
    int*      rs   = (int*)alloc((size_t)(NN + 1) * 4);
    int*      bsum = (int*)alloc((size_t)NB * 4);
    int*      boff = (int*)alloc((size_t)NB * 4);
    int*      flag = (int*)alloc(64);
    int*      rank = (int*)alloc((size_t)NE * 4);       // 6.4 MB
    unsigned* csr  = (unsigned*)alloc((size_t)NE * 4);  // 6.4 MB
    float*    hA   = (float*)alloc((size_t)NN * 64 * 4);
    float*    hB   = (float*)d_out;                     // reuse d_out as layer-1 act

    hipMemsetAsync(cnt, 0, (size_t)NN * 4, stream);
    k_detect<<<1, 64, 0, stream>>>(ei, flag);
    k_count<<<(NE + 255) / 256, 256, 0, stream>>>(ei, flag, cnt, rank);
    k_scan1<<<NB, 256, 0, stream>>>(cnt, bsum, dinv);
    k_scan2<<<1, 64, 0, stream>>>(bsum, boff, rs);
    k_scan3<<<NB, 256, 0, stream>>>(cnt, boff, rs);
    k_fill<<<(NE + 255) / 256, 256, 0, stream>>>(ei, flag, cnt, rs, rank, csr);

    // layer 1
    k_gemm<<<1568, 256, 0, stream>>>(x, W1, hA);
    k_agg<<<(NN * 64) / 256, 256, 0, stream>>>((const float4*)hA, rs, csr, dinv, b1,
                                               (float4*)hB);
    // layer 2
    k_gemm<<<1568, 256, 0, stream>>>(hB, W2, hA);
    k_agg<<<(NN * 64) / 256, 256, 0, stream>>>((const float4*)hA, rs, csr, dinv, b2,
                                               (float4*)d_out);
}

// Round 5
// 379.043 us; speedup vs baseline: 1.8038x; 1.1096x over previous
//
#include <hip/hip_runtime.h>
#include <hip/hip_bf16.h>
#include <stdint.h>

#define NN 100000
#define NE 1600000
#define NB 98                   // ceil(NN/1024) scan blocks

// ---------------- edge_index width detection (int32 vs int64) ----------------

__global__ void k_detect(const int* __restrict__ ei, int* __restrict__ flag) {
    if (threadIdx.x == 0) {
        int z = 0;
#pragma unroll
        for (int i = 0; i < 16; ++i) z |= ei[2 * i + 1];
        flag[0] = (z == 0) ? 1 : 0;
    }
}

// ---------------- CSR build ----------------
// k_count: 8 edges/thread -> 8 independent atomic chains in flight per lane.
// Histogram in-degree AND record each edge's rank (atomic return), coalesced.

__global__ void k_count(const int* __restrict__ ei, const int* __restrict__ flag,
                        int* __restrict__ cnt, int* __restrict__ rank) {
    int base = (blockIdx.x * 256 + threadIdx.x) * 8;
    if (base >= NE) return;                      // NE % 8 == 0: full groups only
    int is64 = flag[0];
    int d[8];
    if (is64) {
        // dst words live at int2 index NE+e; read as int4 pairs {d,hi,d,hi}
        const int4* p = (const int4*)ei;
        int idx = (NE + base) >> 1;              // int4 index
#pragma unroll
        for (int j = 0; j < 4; ++j) {
            int4 v = p[idx + j];
            d[2 * j] = v.x; d[2 * j + 1] = v.z;
        }
    } else {
        int4 a = *(const int4*)&ei[NE + base];
        int4 b = *(const int4*)&ei[NE + base + 4];
        d[0] = a.x; d[1] = a.y; d[2] = a.z; d[3] = a.w;
        d[4] = b.x; d[5] = b.y; d[6] = b.z; d[7] = b.w;
    }
    int r[8];
#pragma unroll
    for (int j = 0; j < 8; ++j) r[j] = atomicAdd(&cnt[d[j]], 1);
    *(int4*)&rank[base] = make_int4(r[0], r[1], r[2], r[3]);
    *(int4*)&rank[base + 4] = make_int4(r[4], r[5], r[6], r[7]);
}

// block-level partial sums for the scan + dinv computation (fused)
__global__ void k_scan1(const int* __restrict__ cnt, int* __restrict__ bsum,
                        float* __restrict__ dinv) {
    __shared__ int sh[256];
    int t = threadIdx.x;
    int base = blockIdx.x * 1024 + t * 4;
    int s = 0;
#pragma unroll
    for (int j = 0; j < 4; ++j) {
        int i = base + j;
        if (i < NN) {
            int c = cnt[i];
            s += c;
            dinv[i] = rsqrtf((float)c + 1.0f);
        }
    }
    sh[t] = s; __syncthreads();
    for (int off = 128; off > 0; off >>= 1) {
        if (t < off) sh[t] += sh[t + off];
        __syncthreads();
    }
    if (t == 0) bsum[blockIdx.x] = sh[0];
}

// one-wave exclusive scan over NB<=128 block sums
__global__ void k_scan2(const int* __restrict__ bsum, int* __restrict__ boff,
                        int* __restrict__ rs) {
    int l = threadIdx.x;                 // 64 threads
    int a = (l < NB) ? bsum[l] : 0;
    int b = (64 + l < NB) ? bsum[64 + l] : 0;
    int ia = a, ib = b;
    for (int off = 1; off < 64; off <<= 1) {
        int t = __shfl_up(ia, off);
        if (l >= off) ia += t;
        t = __shfl_up(ib, off);
        if (l >= off) ib += t;
    }
    int tot_a = __shfl(ia, 63);
    if (l < NB) boff[l] = ia - a;
    if (64 + l < NB) boff[64 + l] = tot_a + ib - b;
    if (l == 0) rs[NN] = NE;
}

__global__ void k_scan3(const int* __restrict__ cnt, const int* __restrict__ boff,
                        int* __restrict__ rs) {
    __shared__ int sh[256];
    int t = threadIdx.x;
    int base = blockIdx.x * 1024 + t * 4;
    int v[4]; int s = 0;
#pragma unroll
    for (int j = 0; j < 4; ++j) { int i = base + j; v[j] = (i < NN) ? cnt[i] : 0; s += v[j]; }
    sh[t] = s; __syncthreads();
    for (int off = 1; off < 256; off <<= 1) {
        int tmp = (t >= off) ? sh[t - off] : 0;
        __syncthreads();
        sh[t] += tmp;
        __syncthreads();
    }
    int run = sh[t] - s + boff[blockIdx.x];
#pragma unroll
    for (int j = 0; j < 4; ++j) {
        int i = base + j;
        if (i < NN) { rs[i] = run; run += v[j]; }
    }
}

// csr entry: (src*16) in bits 0..20 (float4-row base), src in-degree (cap 2047)
// in bits 21..31. Atomic-free: pos = rs[d] + rank[e]. 4 edges/thread for ILP.
__global__ void k_fill(const int* __restrict__ ei, const int* __restrict__ flag,
                       const int* __restrict__ cnt, const int* __restrict__ rs,
                       const int* __restrict__ rank, unsigned* __restrict__ csr) {
    int base = (blockIdx.x * 256 + threadIdx.x) * 4;
    if (base >= NE) return;                      // NE % 4 == 0
    int is64 = flag[0];
    int s[4], d[4];
    if (is64) {
        const int4* p = (const int4*)ei;
#pragma unroll
        for (int j = 0; j < 2; ++j) {
            int4 v = p[(base >> 1) + j];
            s[2 * j] = v.x; s[2 * j + 1] = v.z;
            int4 w = p[((NE + base) >> 1) + j];
            d[2 * j] = w.x; d[2 * j + 1] = w.z;
        }
    } else {
        int4 sv = *(const int4*)&ei[base];
        int4 dv = *(const int4*)&ei[NE + base];
        s[0] = sv.x; s[1] = sv.y; s[2] = sv.z; s[3] = sv.w;
        d[0] = dv.x; d[1] = dv.y; d[2] = dv.z; d[3] = dv.w;
    }
    int4 rk = *(const int4*)&rank[base];
    int rka[4] = {rk.x, rk.y, rk.z, rk.w};
#pragma unroll
    for (int j = 0; j < 4; ++j) {
        int pos = rs[d[j]] + rka[j];
        unsigned deg = (unsigned)min(cnt[s[j]], 2047);
        csr[pos] = ((unsigned)s[j] << 4) | (deg << 21);
    }
}

// ---------------- fp32 GEMM: H[N,64] = X[N,64] @ W[64,64] ----------------
// lane = row: each lane owns one row of a 64-row tile. X loads are
// lane-distinct (1 KB/instruction); W row reads are wave-uniform (scalarize
// to s_load). acc[64] in VGPRs; 256 fma per k4 step.

__global__ void __launch_bounds__(256) k_gemm(const float* __restrict__ X,
                                              const float* __restrict__ W,
                                              float* __restrict__ H) {
    int wid = (blockIdx.x * blockDim.x + threadIdx.x) >> 6;
    int nw = (gridDim.x * blockDim.x) >> 6;
    int lane = threadIdx.x & 63;
    const int ntiles = (NN + 63) >> 6;          // 1563 (last tile ragged)
    for (int t = wid; t < ntiles; t += nw) {
        int row = t * 64 + lane;
        int r = row < NN ? row : NN - 1;        // clamped lanes write duplicate data
        const float4* xp = (const float4*)(X + (size_t)r * 64);
        float acc[64];
#pragma unroll
        for (int c = 0; c < 64; ++c) acc[c] = 0.f;
#pragma unroll 4
        for (int k4 = 0; k4 < 16; ++k4) {
            float4 xv = xp[k4];
#pragma unroll
            for (int kj = 0; kj < 4; ++kj) {
                float xk = (kj == 0) ? xv.x : (kj == 1) ? xv.y : (kj == 2) ? xv.z : xv.w;
                const float4* wr = (const float4*)(W + (k4 * 4 + kj) * 64);
#pragma unroll
                for (int c4 = 0; c4 < 16; ++c4) {
                    float4 wv = wr[c4];
                    acc[c4 * 4 + 0] += xk * wv.x;
                    acc[c4 * 4 + 1] += xk * wv.y;
                    acc[c4 * 4 + 2] += xk * wv.z;
                    acc[c4 * 4 + 3] += xk * wv.w;
                }
            }
        }
        float4* op = (float4*)(H + (size_t)r * 64);
#pragma unroll
        for (int c4 = 0; c4 < 16; ++c4)
            op[c4] = make_float4(acc[c4 * 4], acc[c4 * 4 + 1],
                                 acc[c4 * 4 + 2], acc[c4 * 4 + 3]);
    }
}

// ---------------- aggregation: one wave per node, 16 lanes x float4 per row,
// 4 lane-groups x 4-deep unroll => 16 row-gathers in flight per wave ----------

__global__ void __launch_bounds__(256) k_agg(const float4* __restrict__ h4,
                                             const int* __restrict__ rs,
                                             const unsigned* __restrict__ csr,
                                             const float* __restrict__ dinv,
                                             const float* __restrict__ bias,
                                             float4* __restrict__ out4) {
    int wid = (blockIdx.x * blockDim.x + threadIdx.x) >> 6;
    int lane = threadIdx.x & 63;
    int node = __builtin_amdgcn_readfirstlane(wid);
    if (node >= NN) return;
    int g = lane >> 4;        // edge-slot group 0..3
    int fl = lane & 15;       // feature quad 0..15
    float dn = dinv[node];
    int e0 = rs[node], e1 = rs[node + 1];
    float4 hrow = h4[node * 16 + fl];          // self row
    float ax = 0.f, ay = 0.f, az = 0.f, aw = 0.f;
    int e = e0 + g;
    for (; e + 12 < e1; e += 16) {             // 4 edges per group in flight
        unsigned p0 = csr[e];
        unsigned p1 = csr[e + 4];
        unsigned p2 = csr[e + 8];
        unsigned p3 = csr[e + 12];
        float4 r0 = h4[(p0 & 0x1FFFFFu) + fl];
        float4 r1 = h4[(p1 & 0x1FFFFFu) + fl];
        float4 r2 = h4[(p2 & 0x1FFFFFu) + fl];
        float4 r3 = h4[(p3 & 0x1FFFFFu) + fl];
        float w0 = rsqrtf((float)(p0 >> 21) + 1.0f);
        float w1 = rsqrtf((float)(p1 >> 21) + 1.0f);
        float w2 = rsqrtf((float)(p2 >> 21) + 1.0f);
        float w3 = rsqrtf((float)(p3 >> 21) + 1.0f);
        ax += r0.x * w0; ay += r0.y * w0; az += r0.z * w0; aw += r0.w * w0;
        ax += r1.x * w1; ay += r1.y * w1; az += r1.z * w1; aw += r1.w * w1;
        ax += r2.x * w2; ay += r2.y * w2; az += r2.z * w2; aw += r2.w * w2;
        ax += r3.x * w3; ay += r3.y * w3; az += r3.z * w3; aw += r3.w * w3;
    }
    for (; e < e1; e += 4) {
        unsigned p0 = csr[e];
        float4 r0 = h4[(p0 & 0x1FFFFFu) + fl];
        float w0 = rsqrtf((float)(p0 >> 21) + 1.0f);
        ax += r0.x * w0; ay += r0.y * w0; az += r0.z * w0; aw += r0.w * w0;
    }
    ax += __shfl_xor(ax, 16); ay += __shfl_xor(ay, 16);
    az += __shfl_xor(az, 16); aw += __shfl_xor(aw, 16);
    ax += __shfl_xor(ax, 32); ay += __shfl_xor(ay, 32);
    az += __shfl_xor(az, 32); aw += __shfl_xor(aw, 32);
    if (lane < 16) {
        const float4 b4 = *(const float4*)&bias[fl * 4];
        float4 res;
        res.x = fmaxf((ax + hrow.x * dn) * dn + b4.x, 0.f);
        res.y = fmaxf((ay + hrow.y * dn) * dn + b4.y, 0.f);
        res.z = fmaxf((az + hrow.z * dn) * dn + b4.z, 0.f);
        res.w = fmaxf((aw + hrow.w * dn) * dn + b4.w, 0.f);
        out4[node * 16 + fl] = res;
    }
}

// ---------------- launch ----------------

extern "C" void kernel_launch(void* const* d_in, const int* in_sizes, int n_in,
                              void* d_out, int out_size, void* d_ws, size_t ws_size,
                              hipStream_t stream) {
    const float* x  = (const float*)d_in[0];            // [NN,64] fp32
    const int* ei   = (const int*)d_in[1];              // [2,NE] int32/int64 (detected)
    const float* W1 = (const float*)d_in[2];
    const float* b1 = (const float*)d_in[3];
    const float* W2 = (const float*)d_in[4];
    const float* b2 = (const float*)d_in[5];

    char* ws = (char*)d_ws;
    size_t off = 0;
    auto alloc = [&](size_t bytes) -> char* {
        char* p = ws + off;
        off = (off + bytes + 511) & ~(size_t)511;
        return p;
    };
    int*      cnt  = (int*)alloc((size_t)NN * 4);
    float*    dinv = (float*)alloc((size_t)NN * 4);
    int*      rs   = (int*)alloc((size_t)(NN + 1) * 4);
    int*      bsum = (int*)alloc((size_t)NB * 4);
    int*      boff = (int*)alloc((size_t)NB * 4);
    int*      flag = (int*)alloc(64);
    int*      rank = (int*)alloc((size_t)NE * 4);       // 6.4 MB
    unsigned* csr  = (unsigned*)alloc((size_t)NE * 4);  // 6.4 MB
    float*    hA   = (float*)alloc((size_t)NN * 64 * 4);
    float*    hB   = (float*)d_out;                     // reuse d_out as layer-1 act

    hipMemsetAsync(cnt, 0, (size_t)NN * 4, stream);
    k_detect<<<1, 64, 0, stream>>>(ei, flag);
    k_count<<<(NE / 8 + 255) / 256, 256, 0, stream>>>(ei, flag, cnt, rank);
    k_scan1<<<NB, 256, 0, stream>>>(cnt, bsum, dinv);
    k_scan2<<<1, 64, 0, stream>>>(bsum, boff, rs);
    k_scan3<<<NB, 256, 0, stream>>>(cnt, boff, rs);
    k_fill<<<(NE / 4 + 255) / 256, 256, 0, stream>>>(ei, flag, cnt, rs, rank, csr);

    // layer 1
    k_gemm<<<391, 256, 0, stream>>>(x, W1, hA);
    k_agg<<<(NN * 64) / 256, 256, 0, stream>>>((const float4*)hA, rs, csr, dinv, b1,
                                               (float4*)hB);
    // layer 2
    k_gemm<<<391, 256, 0, stream>>>(hB, W2, hA);
    k_agg<<<(NN * 64) / 256, 256, 0, stream>>>((const float4*)hA, rs, csr, dinv, b2,
                                               (float4*)d_out);
}